// Round 2
// baseline (691.061 us; speedup 1.0000x reference)
//
#include <hip/hip_runtime.h>
#include <math.h>

// Segment-prefix max, R2: DENSE-FRONT restructure.
//
// Theory: previous kernel (1 block per segment) holds 2048 independent read
// cursors scattered over 512 MB -> DRAM row-buffer thrash -> ~1.8 TB/s.
// Patterns proven at ~6.3 TB/s on gfx950 (fill, grid-stride float4 copy)
// advance a dense contiguous front. So: grid-stride over 64-row (32 KB)
// chunks of the flat row space (instantaneous window = 1024 blocks x 32 KB
// = 32 MB contiguous), local LDS reduce per chunk, publish per-column
// partials with atomicMax on monotone-uint-mapped floats.
//
// 3 launches: init (prefix-scan sizes -> ws; out := map(-inf)),
//             main (dense-front reduce + atomic publish),
//             unmap (uint -> float in place, 1 MB).

#define BLOCK 256
#define NB_MAIN 1024
#define CHUNK_ROWS 64
#define MAX_SEG 2560            // LDS starts-table capacity (problem: 2048)

typedef float f32x4 __attribute__((ext_vector_type(4)));

static __device__ __forceinline__ f32x4 fmax4v(f32x4 a, f32x4 b) {
    f32x4 r;
    r.x = fmaxf(a.x, b.x);
    r.y = fmaxf(a.y, b.y);
    r.z = fmaxf(a.z, b.z);
    r.w = fmaxf(a.w, b.w);
    return r;
}

// monotone bijection float -> u32 (order-preserving, so umax == fmax)
static __device__ __forceinline__ unsigned fmap(float x) {
    unsigned b = __float_as_uint(x);
    return (b & 0x80000000u) ? ~b : (b | 0x80000000u);
}
static __device__ __forceinline__ float funmap(unsigned u) {
    return (u & 0x80000000u) ? __uint_as_float(u ^ 0x80000000u)
                             : __uint_as_float(~u);
}

// ---- init: last block scans sizes -> starts[0..n] in ws; others init out ----
__global__ __launch_bounds__(BLOCK)
void init_kernel(const int* __restrict__ sizes, int n,
                 unsigned* __restrict__ out_u, int out_elems,
                 int* __restrict__ starts) {
    if ((int)blockIdx.x == (int)gridDim.x - 1) {
        __shared__ int ssum[BLOCK];
        const int t = threadIdx.x;
        const int per = (n + BLOCK - 1) / BLOCK;      // 8 for n=2048
        int loc[16];                                  // per <= 16 (n <= 4096)
        int s = 0;
        for (int j = 0; j < per && j < 16; ++j) {
            int idx = t * per + j;
            int v = (idx < n) ? sizes[idx] : 0;
            loc[j] = s;
            s += v;
        }
        ssum[t] = s;
        __syncthreads();
        if (t == 0) {
            int run = 0;
            for (int i = 0; i < BLOCK; ++i) { int tmp = ssum[i]; ssum[i] = run; run += tmp; }
            starts[n] = run;                          // total rows
        }
        __syncthreads();
        int off = ssum[t];
        for (int j = 0; j < per && j < 16; ++j) {
            int idx = t * per + j;
            if (idx < n) starts[idx] = off + loc[j];
        }
    } else {
        const int nb = (int)gridDim.x - 1;
        for (int i = blockIdx.x * BLOCK + threadIdx.x; i < out_elems; i += nb * BLOCK)
            out_u[i] = 0x007FFFFFu;                   // fmap(-inf)
    }
}

// ---- main: dense-front chunk reduce ----
__global__ __launch_bounds__(BLOCK)
void seg_max_dense(const float* __restrict__ x,
                   const int* __restrict__ starts_g,
                   const int* __restrict__ wptr,
                   unsigned* __restrict__ out_u,
                   int n, int D) {
    if (n > MAX_SEG) return;                          // shape guard (fixed 2048)
    const int tid  = threadIdx.x;
    const int nc4  = D >> 2;                          // 32
    const int col4 = tid & 31;
    const int rg   = tid >> 5;                        // 0..7

    __shared__ int st[MAX_SEG + 1];
    for (int i = tid; i <= n; i += BLOCK) st[i] = starts_g[i];
    __syncthreads();
    const int total = st[n];
    const int w     = *wptr;
    const int n_chunks = (total + CHUNK_ROWS - 1) / CHUNK_ROWS;

    __shared__ f32x4 part[8][32];

    for (int c = blockIdx.x; c < n_chunks; c += gridDim.x) {
        const int r0 = c * CHUNK_ROWS;
        const int r1 = min(r0 + CHUNK_ROWS, total);

        // greatest s0 with st[s0] <= r0
        int lo = 0, hi = n - 1;
        while (lo < hi) {
            int mid = (lo + hi + 1) >> 1;
            if (st[mid] <= r0) lo = mid; else hi = mid - 1;
        }
        const int s0 = lo;

        if (r1 <= st[s0 + 1]) {
            // fast path: whole chunk in one segment
            const int Ls   = st[s0 + 1] - st[s0] - w + 1;
            const int vend = st[s0] + (Ls > 0 ? Ls : 0);
            const int rend = min(r1, vend);
            int kmax = (rend - r0 - rg + 7) >> 3;     // this thread: rows r0+rg+8k
            kmax = kmax < 0 ? 0 : (kmax > 8 ? 8 : kmax);

            f32x4 acc = { -INFINITY, -INFINITY, -INFINITY, -INFINITY };
            const f32x4* p = (const f32x4*)x + (size_t)(r0 + rg) * nc4 + col4;
            const size_t step = (size_t)nc4 << 3;     // 8 rows
            if (kmax == 8) {
                #pragma unroll
                for (int k = 0; k < 8; ++k) {
                    acc = fmax4v(acc, __builtin_nontemporal_load(p));
                    p += step;
                }
            } else {
                for (int k = 0; k < kmax; ++k) {
                    acc = fmax4v(acc, __builtin_nontemporal_load(p));
                    p += step;
                }
            }
            part[rg][col4] = acc;
            __syncthreads();
            if (tid < 32 && rend > r0) {
                f32x4 a = part[0][tid];
                #pragma unroll
                for (int j = 1; j < 8; ++j) a = fmax4v(a, part[j][tid]);
                unsigned* dst = out_u + ((size_t)s0 * nc4 + tid) * 4;
                atomicMax(dst + 0, fmap(a.x));
                atomicMax(dst + 1, fmap(a.y));
                atomicMax(dst + 2, fmap(a.z));
                atomicMax(dst + 3, fmap(a.w));
            }
            __syncthreads();
        } else {
            // slow path: chunk crosses a segment boundary (never, for uniform
            // 512-row segments with 64-row chunks) — per-row atomics, correct
            // for arbitrary sizes.
            int s = s0;
            for (int k = 0; k < 8; ++k) {
                int r = r0 + rg + (k << 3);
                if (r >= r1) break;
                while (r >= st[s + 1]) ++s;
                int Ls = st[s + 1] - st[s] - w + 1;
                if (r - st[s] < Ls) {
                    f32x4 v = __builtin_nontemporal_load(
                        (const f32x4*)x + (size_t)r * nc4 + col4);
                    unsigned* dst = out_u + ((size_t)s * nc4 + col4) * 4;
                    atomicMax(dst + 0, fmap(v.x));
                    atomicMax(dst + 1, fmap(v.y));
                    atomicMax(dst + 2, fmap(v.z));
                    atomicMax(dst + 3, fmap(v.w));
                }
            }
        }
    }
}

// ---- unmap: u32 -> float in place ----
__global__ __launch_bounds__(BLOCK)
void unmap_kernel(unsigned* __restrict__ u, float* __restrict__ f, int nelem) {
    int i = blockIdx.x * BLOCK + threadIdx.x;
    const int strd = gridDim.x * BLOCK;
    for (; i < nelem; i += strd) f[i] = funmap(u[i]);
}

extern "C" void kernel_launch(void* const* d_in, const int* in_sizes, int n_in,
                              void* d_out, int out_size, void* d_ws, size_t ws_size,
                              hipStream_t stream) {
    const float* x     = (const float*)d_in[0];
    const int*   sizes = (const int*)d_in[1];
    const int*   wptr  = (const int*)d_in[2];

    const int n_seg = in_sizes[1];                    // 2048
    const int D     = out_size / n_seg;               // 128

    unsigned* out_u  = (unsigned*)d_out;
    float*    out_f  = (float*)d_out;
    int*      starts = (int*)d_ws;                    // (n_seg+1) ints

    init_kernel<<<65, BLOCK, 0, stream>>>(sizes, n_seg, out_u, out_size, starts);
    seg_max_dense<<<NB_MAIN, BLOCK, 0, stream>>>(x, starts, wptr, out_u, n_seg, D);
    unmap_kernel<<<256, BLOCK, 0, stream>>>(out_u, out_f, out_size);
}

// Round 3
// 637.641 us; speedup vs baseline: 1.0838x; 1.0838x over previous
//
#include <hip/hip_runtime.h>
#include <math.h>

// Segment-prefix max, R3: revert R2's multi-launch machinery (regressed -52 us),
// keep R1's wins (phase rotation + non-temporal loads), add micro-opts.
//
// Decomposition evidence (R0/R1/R2): three radically different access
// structures land within 8% -> dur_us is dominated by ~545-550 us of fixed
// harness overhead (one 331 us 2-GiB ws poison fill + dozens of tiny reset
// memsets). Kernel-attributable residual at R1 ~= 90 us ~= 5.9 TB/s read,
// i.e. ~94% of achievable read BW. This round: single launch, 1-barrier
// start-scan (shfl instead of 8-barrier LDS tree), dual accumulator chains.

#define BLOCK 256

typedef float f32x4 __attribute__((ext_vector_type(4)));

static __device__ __forceinline__ f32x4 fmax4v(f32x4 a, f32x4 b) {
    f32x4 r;
    r.x = fmaxf(a.x, b.x);
    r.y = fmaxf(a.y, b.y);
    r.z = fmaxf(a.z, b.z);
    r.w = fmaxf(a.w, b.w);
    return r;
}

__global__ __launch_bounds__(BLOCK)
void seg_prefix_max_kernel(const float* __restrict__ x,
                           const int* __restrict__ sizes,
                           const int* __restrict__ wptr,
                           float* __restrict__ out,
                           int n_seg, int D) {
    const int seg = blockIdx.x;
    const int tid = threadIdx.x;
    const int w   = *wptr;

    // ---- start = sum(sizes[0..seg)) : strided partials + 1-barrier reduce ----
    int partial = 0;
    for (int j = tid; j < seg; j += BLOCK) partial += sizes[j];
    #pragma unroll
    for (int o = 32; o > 0; o >>= 1) partial += __shfl_down(partial, o, 64);
    __shared__ int wsum[4];
    if ((tid & 63) == 0) wsum[tid >> 6] = partial;
    __syncthreads();
    const int start = wsum[0] + wsum[1] + wsum[2] + wsum[3];
    const int L     = sizes[seg] - w + 1;     // rows to reduce (510 here)

    // ---- strided max over rows; 32 x float4 lanes cover D=128 ----
    const int nc4  = D >> 2;                  // float4s per row (32)
    const int col4 = tid & 31;
    const int rg   = tid >> 5;                // 0..7 row groups

    f32x4 acc0 = { -INFINITY, -INFINITY, -INFINITY, -INFINITY };
    f32x4 acc1 = acc0;

    {
        const f32x4* base  = (const f32x4*)x + (size_t)start * nc4 + col4;
        const size_t step8 = (size_t)nc4 << 3;            // 8 rows

        // this thread handles rows rg + 8k, k in [0, K)
        const int K  = (L > rg) ? ((L - rg + 7) >> 3) : 0;
        // block-dependent rotation: 64 phases x 4 KiB spans the segment
        const int k0 = ((seg & 63) * K) >> 6;             // in [0, K)

        // [k0, K) with two independent chains
        const f32x4* p = base + (size_t)(rg + (k0 << 3)) * nc4;
        int k = k0;
        #pragma unroll 4
        for (; k + 2 <= K; k += 2) {
            acc0 = fmax4v(acc0, __builtin_nontemporal_load(p));
            acc1 = fmax4v(acc1, __builtin_nontemporal_load(p + step8));
            p += 2 * step8;
        }
        if (k < K) acc0 = fmax4v(acc0, __builtin_nontemporal_load(p));

        // wrap: [0, k0)
        p = base + (size_t)rg * nc4;
        k = 0;
        #pragma unroll 4
        for (; k + 2 <= k0; k += 2) {
            acc0 = fmax4v(acc0, __builtin_nontemporal_load(p));
            acc1 = fmax4v(acc1, __builtin_nontemporal_load(p + step8));
            p += 2 * step8;
        }
        if (k < k0) acc0 = fmax4v(acc0, __builtin_nontemporal_load(p));

        acc0 = fmax4v(acc0, acc1);
    }

    // ---- reduce the 8 row-group partials via LDS ----
    __shared__ f32x4 part[8][32];
    part[rg][col4] = acc0;
    __syncthreads();

    if (tid < 32) {
        f32x4 a = part[0][tid];
        #pragma unroll
        for (int j = 1; j < 8; ++j) a = fmax4v(a, part[j][tid]);
        ((f32x4*)out)[(size_t)seg * 32 + tid] = a;
    }
}

extern "C" void kernel_launch(void* const* d_in, const int* in_sizes, int n_in,
                              void* d_out, int out_size, void* d_ws, size_t ws_size,
                              hipStream_t stream) {
    const float* x     = (const float*)d_in[0];
    const int*   sizes = (const int*)d_in[1];
    const int*   wptr  = (const int*)d_in[2];
    float*       out   = (float*)d_out;

    const int n_seg = in_sizes[1];            // 2048
    const int D     = out_size / n_seg;       // 128

    seg_prefix_max_kernel<<<n_seg, BLOCK, 0, stream>>>(x, sizes, wptr, out, n_seg, D);
}